// Round 3
// baseline (1413.215 us; speedup 1.0000x reference)
//
#include <hip/hip_runtime.h>

// MPNNLSTM round 2: barrier-free wave-owned LSTM (16 nodes/wave, MFMA, no
// __syncthreads) + bf16 SpMM gathers + fast sigmoid/tanh (v_exp/v_rcp).

#define N_TOT 140000
#define NE    2240000
#define NODES 20000
#define TWIN  7
#define CIN   8
#define HD    64
#define OUTC  142
#define NB_SCAN 137       // ceil(140000/1024)
#define NTILES 1250       // 20000/16 node-tiles per step

typedef __attribute__((ext_vector_type(8))) short short8;
typedef __attribute__((ext_vector_type(4))) float f32x4;

static __device__ __forceinline__ float fast_exp2(float x) {
  return __builtin_amdgcn_exp2f(x);
}
static __device__ __forceinline__ float fast_rcp(float x) {
  return __builtin_amdgcn_rcpf(x);
}
static __device__ __forceinline__ float sigf(float x) {
  // 1/(1+exp(-x)) = rcp(1 + exp2(-x*log2e))
  return fast_rcp(1.0f + fast_exp2(-1.4426950408889634f * x));
}
static __device__ __forceinline__ float tanhf_(float x) {
  // 1 - 2/(exp(2x)+1)
  return 1.0f - 2.0f * fast_rcp(1.0f + fast_exp2(2.8853900817779268f * x));
}
static __device__ __forceinline__ ushort f2bf(float x) {
  union { float f; uint32_t u; } c; c.f = x;
  uint32_t r = c.u + 0x7fff + ((c.u >> 16) & 1);   // RNE
  return (ushort)(r >> 16);
}
static __device__ __forceinline__ float bf2f(ushort h) {
  union { uint32_t u; float f; } c; c.u = ((uint32_t)h) << 16; return c.f;
}

__global__ __launch_bounds__(256) void k_init_deg(float* __restrict__ deg) {
  int i = blockIdx.x * 256 + threadIdx.x;
  if (i < N_TOT) deg[i] = 1.0f;   // self-loop weight
}

// Pack W [256][K] (row-major f32) into MFMA B-fragment order:
// Wp[((kc*16 + nt)*64 + lane)*8 + j] = bf16( W[nt*16+(lane&15)][kc*32+(lane>>4)*8+j] )
__global__ __launch_bounds__(256) void k_pack(const float* __restrict__ W,
                                              ushort* __restrict__ Wp, int K) {
  int idx = blockIdx.x * 256 + threadIdx.x;
  int total = (K >> 5) * 16 * 64 * 8;
  if (idx < total) {
    int j = idx & 7, lane = (idx >> 3) & 63, nt = (idx >> 9) & 15, kc = idx >> 13;
    int g = nt * 16 + (lane & 15);
    int k = kc * 32 + ((lane >> 4) << 3) + j;
    Wp[idx] = f2bf(W[g * K + k]);
  }
}

__global__ __launch_bounds__(256) void k_bsum(const float* __restrict__ bih1,
                                              const float* __restrict__ bhh1,
                                              const float* __restrict__ bih2,
                                              const float* __restrict__ bhh2,
                                              float* __restrict__ bsum1,
                                              float* __restrict__ bsum2) {
  int t = threadIdx.x;
  if (blockIdx.x == 0) bsum1[t] = bih1[t] + bhh1[t];
  else                 bsum2[t] = bih2[t] + bhh2[t];
}

__global__ __launch_bounds__(256) void k_deg_cnt(const int* __restrict__ srcI,
                                                 const int* __restrict__ dstI,
                                                 const float* __restrict__ w,
                                                 float* deg, int* cnt) {
  int e = blockIdx.x * 256 + threadIdx.x;
  if (e < NE) {
    int d = dstI[e];
    atomicAdd(&deg[d], w[e]);
    atomicAdd(&cnt[d], 1);
  }
}

__global__ __launch_bounds__(256) void k_dinv(const float* __restrict__ deg,
                                              float* __restrict__ dinv) {
  int i = blockIdx.x * 256 + threadIdx.x;
  if (i < N_TOT) dinv[i] = rsqrtf(deg[i]);
}

// ---- 3-phase exclusive scan of cnt -> rowptr (chunk = 1024) ----
__global__ __launch_bounds__(256) void k_scan_a(const int* __restrict__ cnt,
                                                int* __restrict__ bsum, int n) {
  __shared__ int sd[256];
  int b = blockIdx.x, t = threadIdx.x;
  int s = 0;
  for (int i = t; i < 1024; i += 256) {
    int idx = b * 1024 + i;
    s += (idx < n) ? cnt[idx] : 0;
  }
  sd[t] = s; __syncthreads();
  for (int off = 128; off > 0; off >>= 1) {
    if (t < off) sd[t] += sd[t + off];
    __syncthreads();
  }
  if (t == 0) bsum[b] = sd[0];
}

__global__ __launch_bounds__(64) void k_scan_b(int* __restrict__ bsum, int nb) {
  if (threadIdx.x == 0 && blockIdx.x == 0) {
    int acc = 0;
    for (int i = 0; i < nb; ++i) { int v = bsum[i]; bsum[i] = acc; acc += v; }
  }
}

__global__ __launch_bounds__(256) void k_scan_c(const int* __restrict__ cnt,
                                                const int* __restrict__ bsum,
                                                int* __restrict__ rowptr, int n, int etot) {
  __shared__ int tsum[256];
  int b = blockIdx.x, t = threadIdx.x;
  int base = b * 1024 + t * 4;
  int v[4]; int s = 0;
  #pragma unroll
  for (int i = 0; i < 4; ++i) { int idx = base + i; v[i] = (idx < n) ? cnt[idx] : 0; s += v[i]; }
  tsum[t] = s; __syncthreads();
  for (int off = 1; off < 256; off <<= 1) {
    int xv = 0;
    if (t >= off) xv = tsum[t - off];
    __syncthreads();
    if (t >= off) tsum[t] += xv;
    __syncthreads();
  }
  int excl = bsum[b] + ((t > 0) ? tsum[t - 1] : 0);
  #pragma unroll
  for (int i = 0; i < 4; ++i) {
    int idx = base + i;
    if (idx < n) { rowptr[idx] = excl; excl += v[i]; }
  }
  if (b == 0 && t == 0) rowptr[n] = etot;
}

__global__ __launch_bounds__(256) void k_fill(const int* __restrict__ srcI,
                                              const int* __restrict__ dstI,
                                              const float* __restrict__ w,
                                              const float* __restrict__ dinv,
                                              const int* __restrict__ rowptr,
                                              int* cursor,
                                              int* __restrict__ colA,
                                              float* __restrict__ valA) {
  int e = blockIdx.x * 256 + threadIdx.x;
  if (e < NE) {
    int s = srcI[e], d = dstI[e];
    int pos = atomicAdd(&cursor[d], 1);
    int i = rowptr[d] + pos;
    colA[i] = s;
    valA[i] = dinv[s] * w[e] * dinv[d];
  }
}

// H0 = bf16( x @ W1 )   ([N,8] @ [8,64]); wave per row, lane = out channel
__global__ __launch_bounds__(256) void k_gemm_in(const float* __restrict__ x,
                                                 const float* __restrict__ W1,
                                                 ushort* __restrict__ H0) {
  __shared__ float w[CIN * HD];
  for (int i = threadIdx.x; i < CIN * HD; i += 256) w[i] = W1[i];
  __syncthreads();
  int wid = (blockIdx.x * 256 + threadIdx.x) >> 6;
  int lane = threadIdx.x & 63;
  int nw = (gridDim.x * 256) >> 6;
  for (int n = wid; n < N_TOT; n += nw) {
    float acc = 0.f;
    #pragma unroll
    for (int c = 0; c < CIN; ++c) acc += x[n * CIN + c] * w[c * HD + lane];
    H0[n * HD + lane] = f2bf(acc);
  }
}

// out[d] = relu( dinv^2*Hin[d] + sum val*Hin[col] + bias ); bf16 gathers, BN stats
__global__ __launch_bounds__(256) void k_spmm(const ushort* __restrict__ Hin,
                                              const float* __restrict__ dinv,
                                              const int* __restrict__ rowptr,
                                              const int* __restrict__ colA,
                                              const float* __restrict__ valA,
                                              const float* __restrict__ bias,
                                              float* __restrict__ Aout,
                                              float* gsum, float* gsq) {
  int wid = (blockIdx.x * 256 + threadIdx.x) >> 6;
  int lane = threadIdx.x & 63;
  int nw = (gridDim.x * 256) >> 6;
  float b = bias[lane];
  float s = 0.f, q = 0.f;
  for (int d = wid; d < N_TOT; d += nw) {
    float di = dinv[d];
    float acc = di * di * bf2f(Hin[(size_t)d * HD + lane]);
    int beg = rowptr[d], end = rowptr[d + 1];
    #pragma unroll 4
    for (int i = beg; i < end; ++i) {
      int c = colA[i];
      float v = valA[i];
      acc += v * bf2f(Hin[(size_t)c * HD + lane]);
    }
    float r = fmaxf(acc + b, 0.f);
    Aout[(size_t)d * HD + lane] = r;
    s += r; q += r * r;
  }
  atomicAdd(&gsum[lane], s);
  atomicAdd(&gsq[lane], q);
}

__global__ __launch_bounds__(64) void k_bnfin(const float* __restrict__ gsum,
                                              const float* __restrict__ gsq,
                                              const float* __restrict__ gamma,
                                              const float* __restrict__ beta,
                                              float* __restrict__ scale,
                                              float* __restrict__ shift) {
  int j = threadIdx.x;
  if (j < HD) {
    float m = gsum[j] / (float)N_TOT;
    float v = gsq[j] / (float)N_TOT - m * m;
    float sc = gamma[j] * rsqrtf(v + 1e-5f);
    scale[j] = sc;
    shift[j] = beta[j] - m * sc;
  }
}

// Hb = bf16( BN1(A1) @ W2 )  ([N,64]@[64,64]); wave per row; W2 is [k][j] layout
__global__ __launch_bounds__(256) void k_gemm_h(const float* __restrict__ A1,
                                                const float* __restrict__ scale,
                                                const float* __restrict__ shift,
                                                const float* __restrict__ W2,
                                                ushort* __restrict__ Hb) {
  __shared__ float w[HD * HD];
  for (int i = threadIdx.x; i < HD * HD; i += 256) w[i] = W2[i];
  __syncthreads();
  int wid = (blockIdx.x * 256 + threadIdx.x) >> 6;
  int lane = threadIdx.x & 63;
  int nw = (gridDim.x * 256) >> 6;
  float sc = scale[lane], sh = shift[lane];
  for (int n = wid; n < N_TOT; n += nw) {
    float xj = sc * A1[(size_t)n * HD + lane] + sh;
    float acc = 0.f;
    #pragma unroll 8
    for (int k = 0; k < HD; ++k) acc += __shfl(xj, k, 64) * w[k * HD + lane];
    Hb[(size_t)n * HD + lane] = f2bf(acc);
  }
}

// Pack BN'd [BN1(A1)|BN2(A2)] into MFMA A-fragment layout, bf16:
// Xcp[(((step*NTILES+tile)*4+kc)*64+lane)*8 + j] =
//   Xc[step*NODES + tile*16 + (lane&15)][kc*32 + (lane>>4)*8 + j]
__global__ __launch_bounds__(256) void k_xcprep(const float* __restrict__ A1,
                                                const float* __restrict__ A2,
                                                const float* __restrict__ scale1,
                                                const float* __restrict__ shift1,
                                                const float* __restrict__ scale2,
                                                const float* __restrict__ shift2,
                                                ushort* __restrict__ Xcp) {
  int tid = blockIdx.x * 256 + threadIdx.x;       // one 16B unit (8 bf16)
  if (tid >= N_TOT * 128 / 8) return;
  int lane = tid & 63;
  int rest = tid >> 6;
  int kc = rest & 3;
  int st = rest >> 2;                              // step*NTILES + tile
  int step = st / NTILES;
  int tile = st - step * NTILES;
  int node = step * NODES + tile * 16 + (lane & 15);
  int k = kc * 32 + ((lane >> 4) << 3);
  const float* src; const float* sc; const float* sh;
  if (k < HD) { src = A1 + (size_t)node * HD + k;        sc = scale1 + k;      sh = shift1 + k; }
  else        { src = A2 + (size_t)node * HD + (k - HD); sc = scale2 + k - HD; sh = shift2 + k - HD; }
  ushort v[8];
  #pragma unroll
  for (int j = 0; j < 8; ++j) v[j] = f2bf(sc[j] * src[j] + sh[j]);
  *reinterpret_cast<short8*>(&Xcp[(size_t)tid * 8]) = *reinterpret_cast<short8*>(v);
}

// ---------------------------------------------------------------------------
// Barrier-free fused 2-layer LSTM. One WAVE owns 16 nodes for all 7 steps.
// Gates: full 256 cols per wave (16 n-tiles), MFMA 16x16x32 bf16.
// C/D layout => lane (g=lane>>4, c=lane&15) holds rows g*4..g*4+3 and, across
// nt, all four gates for channels {c, c+16, c+32, c+48}: elementwise update is
// lane-local. h relayout to A-frags via tiny per-wave swizzled LDS buffer.
// ---------------------------------------------------------------------------
__global__ __launch_bounds__(256) void k_lstm3(const ushort* __restrict__ Xcp,
                                               const ushort* __restrict__ Wp1,
                                               const ushort* __restrict__ Wphh1,
                                               const ushort* __restrict__ Wpih2,
                                               const ushort* __restrict__ Wphh2,
                                               const float* __restrict__ bsum1,
                                               const float* __restrict__ bsum2,
                                               float* __restrict__ out) {
  __shared__ ushort hbuf[4 * 2 * 1024];   // per wave: h1[16][64], h2[16][64] (swizzled)
  int t = threadIdx.x;
  int wid = t >> 6, lane = t & 63;
  int tile = blockIdx.x * 4 + wid;
  if (tile >= NTILES) return;
  int g = lane >> 4, c = lane & 15;
  ushort* hb1 = &hbuf[(wid * 2 + 0) * 1024];
  ushort* hb2 = &hbuf[(wid * 2 + 1) * 1024];

  float b1v[16], b2v[16];
  #pragma unroll
  for (int nt = 0; nt < 16; ++nt) {
    b1v[nt] = bsum1[c + nt * 16];
    b2v[nt] = bsum2[c + nt * 16];
  }
  float c1[16], c2[16];
  #pragma unroll
  for (int i = 0; i < 16; ++i) { c1[i] = 0.f; c2[i] = 0.f; }

  // h write indices (ushort units, swizzled: idx ^ ((row&7)<<3))
  int hw[16];
  #pragma unroll
  for (int q = 0; q < 4; ++q)
    #pragma unroll
    for (int jr = 0; jr < 4; ++jr) {
      int r = g * 4 + jr, j = c + 16 * q;
      hw[q * 4 + jr] = (r * 64 + j) ^ ((r & 7) << 3);
    }
  // h A-frag read indices per kc
  int hr[2];
  #pragma unroll
  for (int kc = 0; kc < 2; ++kc)
    hr[kc] = (c * 64 + kc * 32 + g * 8) ^ ((c & 7) << 3);

  f32x4 acc[16];
  for (int step = 0; step < TWIN; ++step) {
    // ===== layer 1: gates = Xc @ Wih1^T + h1 @ Whh1^T + b =====
    #pragma unroll
    for (int nt = 0; nt < 16; ++nt)
      acc[nt] = (f32x4){b1v[nt], b1v[nt], b1v[nt], b1v[nt]};
    const ushort* xp = Xcp + ((size_t)(step * NTILES + tile) * 256 + lane) * 8;
    #pragma unroll
    for (int kc = 0; kc < 4; ++kc) {
      short8 a = *reinterpret_cast<const short8*>(xp + (size_t)kc * 512);
      const ushort* wp = Wp1 + ((kc * 16) * 64 + lane) * 8;
      #pragma unroll
      for (int nt = 0; nt < 16; ++nt) {
        short8 b = *reinterpret_cast<const short8*>(wp + nt * 512);
        acc[nt] = __builtin_amdgcn_mfma_f32_16x16x32_bf16(a, b, acc[nt], 0, 0, 0);
      }
    }
    if (step > 0) {
      #pragma unroll
      for (int kc = 0; kc < 2; ++kc) {
        short8 a = *reinterpret_cast<const short8*>(&hb1[hr[kc]]);
        const ushort* wp = Wphh1 + ((kc * 16) * 64 + lane) * 8;
        #pragma unroll
        for (int nt = 0; nt < 16; ++nt) {
          short8 b = *reinterpret_cast<const short8*>(wp + nt * 512);
          acc[nt] = __builtin_amdgcn_mfma_f32_16x16x32_bf16(a, b, acc[nt], 0, 0, 0);
        }
      }
    }
    // elementwise update layer 1 (lane-local; gates i,f,g,o at nt = G*4+q)
    #pragma unroll
    for (int q = 0; q < 4; ++q) {
      #pragma unroll
      for (int jr = 0; jr < 4; ++jr) {
        float gi = acc[q][jr], gf = acc[4 + q][jr];
        float gg = acc[8 + q][jr], go = acc[12 + q][jr];
        float cc = sigf(gf) * c1[q * 4 + jr] + sigf(gi) * tanhf_(gg);
        c1[q * 4 + jr] = cc;
        float h = sigf(go) * tanhf_(cc);
        hb1[hw[q * 4 + jr]] = f2bf(h);
        if (step == TWIN - 1) {
          int r = g * 4 + jr, j = c + 16 * q;
          out[(size_t)(tile * 16 + r) * OUTC + j] = h;
        }
      }
    }
    // ===== layer 2: gates = h1 @ Wih2^T + h2 @ Whh2^T + b =====
    #pragma unroll
    for (int nt = 0; nt < 16; ++nt)
      acc[nt] = (f32x4){b2v[nt], b2v[nt], b2v[nt], b2v[nt]};
    #pragma unroll
    for (int kc = 0; kc < 2; ++kc) {
      short8 a = *reinterpret_cast<const short8*>(&hb1[hr[kc]]);
      const ushort* wp = Wpih2 + ((kc * 16) * 64 + lane) * 8;
      #pragma unroll
      for (int nt = 0; nt < 16; ++nt) {
        short8 b = *reinterpret_cast<const short8*>(wp + nt * 512);
        acc[nt] = __builtin_amdgcn_mfma_f32_16x16x32_bf16(a, b, acc[nt], 0, 0, 0);
      }
    }
    if (step > 0) {
      #pragma unroll
      for (int kc = 0; kc < 2; ++kc) {
        short8 a = *reinterpret_cast<const short8*>(&hb2[hr[kc]]);
        const ushort* wp = Wphh2 + ((kc * 16) * 64 + lane) * 8;
        #pragma unroll
        for (int nt = 0; nt < 16; ++nt) {
          short8 b = *reinterpret_cast<const short8*>(wp + nt * 512);
          acc[nt] = __builtin_amdgcn_mfma_f32_16x16x32_bf16(a, b, acc[nt], 0, 0, 0);
        }
      }
    }
    // elementwise update layer 2
    #pragma unroll
    for (int q = 0; q < 4; ++q) {
      #pragma unroll
      for (int jr = 0; jr < 4; ++jr) {
        float gi = acc[q][jr], gf = acc[4 + q][jr];
        float gg = acc[8 + q][jr], go = acc[12 + q][jr];
        float cc = sigf(gf) * c2[q * 4 + jr] + sigf(gi) * tanhf_(gg);
        c2[q * 4 + jr] = cc;
        float h = sigf(go) * tanhf_(cc);
        hb2[hw[q * 4 + jr]] = f2bf(h);
        if (step == TWIN - 1) {
          int r = g * 4 + jr, j = c + 16 * q;
          out[(size_t)(tile * 16 + r) * OUTC + HD + j] = h;
        }
      }
    }
  }
}

// skip connection S -> out cols 128..141
__global__ __launch_bounds__(256) void k_out_s(const float* __restrict__ x,
                                               float* __restrict__ out) {
  int idx = blockIdx.x * 256 + threadIdx.x;
  if (idx < NODES * 14) {
    int n = idx / 14, c = idx - n * 14;
    float v = (c < CIN) ? x[n * CIN + c]
                        : x[((c - (CIN - 1)) * NODES + n) * CIN + (CIN - 1)];
    out[(size_t)n * OUTC + 128 + c] = v;
  }
}

extern "C" void kernel_launch(void* const* d_in, const int* in_sizes, int n_in,
                              void* d_out, int out_size, void* d_ws, size_t ws_size,
                              hipStream_t stream) {
  const float* x      = (const float*)d_in[0];
  const int*   ei     = (const int*)d_in[1];
  const float* ew     = (const float*)d_in[2];
  const float* W1     = (const float*)d_in[3];
  const float* b1     = (const float*)d_in[4];
  const float* W2     = (const float*)d_in[5];
  const float* b2     = (const float*)d_in[6];
  const float* gamma1 = (const float*)d_in[7];
  const float* beta1  = (const float*)d_in[8];
  const float* gamma2 = (const float*)d_in[9];
  const float* beta2  = (const float*)d_in[10];
  const float* Wih1   = (const float*)d_in[11];
  const float* Whh1   = (const float*)d_in[12];
  const float* bih1   = (const float*)d_in[13];
  const float* bhh1   = (const float*)d_in[14];
  const float* Wih2   = (const float*)d_in[15];
  const float* Whh2   = (const float*)d_in[16];
  const float* bih2   = (const float*)d_in[17];
  const float* bhh2   = (const float*)d_in[18];
  const int* srcI = ei;
  const int* dstI = ei + NE;
  float* out = (float*)d_out;

  char* base = (char*)d_ws;
  size_t off = 0;
  auto alloc = [&](size_t bytes) -> void* {
    void* p = base + off;
    off = (off + bytes + 255) & ~(size_t)255;
    return p;
  };
  // persistent small
  float* deg    = (float*)alloc(N_TOT * 4);
  float* dinv   = (float*)alloc(N_TOT * 4);
  int*   rowptr = (int*)alloc((N_TOT + 1) * 4);
  int*   bsum   = (int*)alloc(NB_SCAN * 4);
  ushort* Wp1   = (ushort*)alloc(32768 * 2);   // [4kc][16nt][64][8]
  ushort* Wphh1 = (ushort*)alloc(16384 * 2);   // [2kc][16nt][64][8]
  ushort* Wpih2 = (ushort*)alloc(16384 * 2);
  ushort* Wphh2 = (ushort*)alloc(16384 * 2);
  float* bsum1  = (float*)alloc(256 * 4);
  float* bsum2  = (float*)alloc(256 * 4);
  float* scale1 = (float*)alloc(HD * 4);
  float* shift1 = (float*)alloc(HD * 4);
  float* scale2 = (float*)alloc(HD * 4);
  float* shift2 = (float*)alloc(HD * 4);
  // zeroed-every-call region (contiguous)
  char* zstart = base + off;
  int*   cnt    = (int*)alloc(N_TOT * 4);
  int*   cursor = (int*)alloc(N_TOT * 4);
  float* sum1   = (float*)alloc(HD * 4);
  float* sq1    = (float*)alloc(HD * 4);
  float* sum2   = (float*)alloc(HD * 4);
  float* sq2    = (float*)alloc(HD * 4);
  size_t zbytes = (size_t)((base + off) - zstart);
  // big buffers. Xcp (35.84 MB) aliases [colA|valA|H0] (8.96+8.96+17.92 MB),
  // which are all dead by the time k_xcprep runs.
  char* bigbase = base + off;
  int*    colA = (int*)alloc((size_t)NE * 4);
  float*  valA = (float*)alloc((size_t)NE * 4);
  ushort* H0   = (ushort*)alloc((size_t)N_TOT * HD * 2);
  ushort* Xcp  = (ushort*)bigbase;
  float* A1   = (float*)alloc((size_t)N_TOT * HD * 4);
  float* A2   = (float*)alloc((size_t)N_TOT * HD * 4);

  hipMemsetAsync(zstart, 0, zbytes, stream);
  k_init_deg<<<(N_TOT + 255) / 256, 256, 0, stream>>>(deg);
  k_pack<<<(32768 + 255) / 256, 256, 0, stream>>>(Wih1, Wp1, 128);
  k_pack<<<(16384 + 255) / 256, 256, 0, stream>>>(Whh1, Wphh1, 64);
  k_pack<<<(16384 + 255) / 256, 256, 0, stream>>>(Wih2, Wpih2, 64);
  k_pack<<<(16384 + 255) / 256, 256, 0, stream>>>(Whh2, Wphh2, 64);
  k_bsum<<<2, 256, 0, stream>>>(bih1, bhh1, bih2, bhh2, bsum1, bsum2);
  k_deg_cnt<<<(NE + 255) / 256, 256, 0, stream>>>(srcI, dstI, ew, deg, cnt);
  k_dinv<<<(N_TOT + 255) / 256, 256, 0, stream>>>(deg, dinv);
  k_scan_a<<<NB_SCAN, 256, 0, stream>>>(cnt, bsum, N_TOT);
  k_scan_b<<<1, 64, 0, stream>>>(bsum, NB_SCAN);
  k_scan_c<<<NB_SCAN, 256, 0, stream>>>(cnt, bsum, rowptr, N_TOT, NE);
  k_fill<<<(NE + 255) / 256, 256, 0, stream>>>(srcI, dstI, ew, dinv, rowptr, cursor, colA, valA);
  k_gemm_in<<<512, 256, 0, stream>>>(x, W1, H0);
  k_spmm<<<1024, 256, 0, stream>>>(H0, dinv, rowptr, colA, valA, b1, A1, sum1, sq1);
  k_bnfin<<<1, 64, 0, stream>>>(sum1, sq1, gamma1, beta1, scale1, shift1);
  k_gemm_h<<<512, 256, 0, stream>>>(A1, scale1, shift1, W2, H0);
  k_spmm<<<1024, 256, 0, stream>>>(H0, dinv, rowptr, colA, valA, b2, A2, sum2, sq2);
  k_bnfin<<<1, 64, 0, stream>>>(sum2, sq2, gamma2, beta2, scale2, shift2);
  k_xcprep<<<(N_TOT * 128 / 8 + 255) / 256, 256, 0, stream>>>(A1, A2, scale1, shift1,
                                                              scale2, shift2, Xcp);
  k_lstm3<<<(NTILES + 3) / 4, 256, 0, stream>>>(Xcp, Wp1, Wphh1, Wpih2, Wphh2,
                                                bsum1, bsum2, out);
  k_out_s<<<(NODES * 14 + 255) / 256, 256, 0, stream>>>(x, out);
}

// Round 4
// 977.506 us; speedup vs baseline: 1.4457x; 1.4457x over previous
//
#include <hip/hip_runtime.h>

// MPNNLSTM round 3:
//  - q-split wave-owned LSTM (acc[4] not acc[16]; no spill; parity-dbuf h in LDS)
//  - BN folded into packed Wih1 + bias  -> LSTM reads raw A1/A2 bf16 fragments
//  - GCN layer 1: aggregate 8-dim x first (gather 32B/edge), fused with W1+BN-stats
//  - CSR as int2 (single 8B scattered write per edge); A1/A2/Hb stored bf16

#define N_TOT 140000
#define NE    2240000
#define NODES 20000
#define TWIN  7
#define CIN   8
#define HD    64
#define OUTC  142
#define NB_SCAN 137       // ceil(140000/1024)
#define NTILES 1250       // 20000/16 node-tiles

typedef __attribute__((ext_vector_type(8))) short short8;
typedef __attribute__((ext_vector_type(4))) float f32x4;

static __device__ __forceinline__ float fast_exp2(float x) {
  return __builtin_amdgcn_exp2f(x);
}
static __device__ __forceinline__ float fast_rcp(float x) {
  return __builtin_amdgcn_rcpf(x);
}
static __device__ __forceinline__ float sigf(float x) {
  return fast_rcp(1.0f + fast_exp2(-1.4426950408889634f * x));
}
static __device__ __forceinline__ float tanhf_(float x) {
  return 1.0f - 2.0f * fast_rcp(1.0f + fast_exp2(2.8853900817779268f * x));
}
static __device__ __forceinline__ ushort f2bf(float x) {
  union { float f; uint32_t u; } c; c.f = x;
  uint32_t r = c.u + 0x7fff + ((c.u >> 16) & 1);   // RNE
  return (ushort)(r >> 16);
}
static __device__ __forceinline__ float bf2f(ushort h) {
  union { uint32_t u; float f; } c; c.u = ((uint32_t)h) << 16; return c.f;
}

__global__ __launch_bounds__(256) void k_init_deg(float* __restrict__ deg) {
  int i = blockIdx.x * 256 + threadIdx.x;
  if (i < N_TOT) deg[i] = 1.0f;   // self-loop weight
}

// Pack W [256][K] (row-major f32) into MFMA B-fragment order.
__global__ __launch_bounds__(256) void k_pack(const float* __restrict__ W,
                                              ushort* __restrict__ Wp, int K) {
  int idx = blockIdx.x * 256 + threadIdx.x;
  int total = (K >> 5) * 16 * 64 * 8;
  if (idx < total) {
    int j = idx & 7, lane = (idx >> 3) & 63, nt = (idx >> 9) & 15, kc = idx >> 13;
    int g = nt * 16 + (lane & 15);
    int k = kc * 32 + ((lane >> 4) << 3) + j;
    Wp[idx] = f2bf(W[g * K + k]);
  }
}

// Pack Wih1 [256][128] with per-k BN scale folded in (k<64: scale1, else scale2).
__global__ __launch_bounds__(256) void k_pack_s(const float* __restrict__ W,
                                                const float* __restrict__ scale1,
                                                const float* __restrict__ scale2,
                                                ushort* __restrict__ Wp) {
  int idx = blockIdx.x * 256 + threadIdx.x;
  if (idx < 32768) {
    int j = idx & 7, lane = (idx >> 3) & 63, nt = (idx >> 9) & 15, kc = idx >> 13;
    int g = nt * 16 + (lane & 15);
    int k = kc * 32 + ((lane >> 4) << 3) + j;
    float s = (k < HD) ? scale1[k] : scale2[k - HD];
    Wp[idx] = f2bf(W[g * 128 + k] * s);
  }
}

// biasL1[col] = bih1+bhh1 + sum_k Wih1[col][k]*shift_k   (BN shift folded)
__global__ __launch_bounds__(256) void k_bias1(const float* __restrict__ Wih1,
                                               const float* __restrict__ bih1,
                                               const float* __restrict__ bhh1,
                                               const float* __restrict__ shift1,
                                               const float* __restrict__ shift2,
                                               float* __restrict__ biasL1) {
  int col = threadIdx.x;
  float s = bih1[col] + bhh1[col];
  for (int k = 0; k < HD; ++k) s += Wih1[col * 128 + k] * shift1[k];
  for (int k = 0; k < HD; ++k) s += Wih1[col * 128 + HD + k] * shift2[k];
  biasL1[col] = s;
}

__global__ __launch_bounds__(256) void k_bsum2(const float* __restrict__ bih2,
                                               const float* __restrict__ bhh2,
                                               float* __restrict__ bsum2) {
  int t = threadIdx.x;
  bsum2[t] = bih2[t] + bhh2[t];
}

__global__ __launch_bounds__(256) void k_deg_cnt(const int* __restrict__ srcI,
                                                 const int* __restrict__ dstI,
                                                 const float* __restrict__ w,
                                                 float* deg, int* cnt) {
  int e = blockIdx.x * 256 + threadIdx.x;
  if (e < NE) {
    int d = dstI[e];
    atomicAdd(&deg[d], w[e]);
    atomicAdd(&cnt[d], 1);
  }
}

__global__ __launch_bounds__(256) void k_dinv(const float* __restrict__ deg,
                                              float* __restrict__ dinv) {
  int i = blockIdx.x * 256 + threadIdx.x;
  if (i < N_TOT) dinv[i] = rsqrtf(deg[i]);
}

// ---- 3-phase exclusive scan of cnt -> rowptr (chunk = 1024) ----
__global__ __launch_bounds__(256) void k_scan_a(const int* __restrict__ cnt,
                                                int* __restrict__ bsum, int n) {
  __shared__ int sd[256];
  int b = blockIdx.x, t = threadIdx.x;
  int s = 0;
  for (int i = t; i < 1024; i += 256) {
    int idx = b * 1024 + i;
    s += (idx < n) ? cnt[idx] : 0;
  }
  sd[t] = s; __syncthreads();
  for (int off = 128; off > 0; off >>= 1) {
    if (t < off) sd[t] += sd[t + off];
    __syncthreads();
  }
  if (t == 0) bsum[b] = sd[0];
}

__global__ __launch_bounds__(64) void k_scan_b(int* __restrict__ bsum, int nb) {
  if (threadIdx.x == 0 && blockIdx.x == 0) {
    int acc = 0;
    for (int i = 0; i < nb; ++i) { int v = bsum[i]; bsum[i] = acc; acc += v; }
  }
}

__global__ __launch_bounds__(256) void k_scan_c(const int* __restrict__ cnt,
                                                const int* __restrict__ bsum,
                                                int* __restrict__ rowptr, int n, int etot) {
  __shared__ int tsum[256];
  int b = blockIdx.x, t = threadIdx.x;
  int base = b * 1024 + t * 4;
  int v[4]; int s = 0;
  #pragma unroll
  for (int i = 0; i < 4; ++i) { int idx = base + i; v[i] = (idx < n) ? cnt[idx] : 0; s += v[i]; }
  tsum[t] = s; __syncthreads();
  for (int off = 1; off < 256; off <<= 1) {
    int xv = 0;
    if (t >= off) xv = tsum[t - off];
    __syncthreads();
    if (t >= off) tsum[t] += xv;
    __syncthreads();
  }
  int excl = bsum[b] + ((t > 0) ? tsum[t - 1] : 0);
  #pragma unroll
  for (int i = 0; i < 4; ++i) {
    int idx = base + i;
    if (idx < n) { rowptr[idx] = excl; excl += v[i]; }
  }
  if (b == 0 && t == 0) rowptr[n] = etot;
}

__global__ __launch_bounds__(256) void k_fill(const int* __restrict__ srcI,
                                              const int* __restrict__ dstI,
                                              const float* __restrict__ w,
                                              const float* __restrict__ dinv,
                                              const int* __restrict__ rowptr,
                                              int* cursor,
                                              int2* __restrict__ csr) {
  int e = blockIdx.x * 256 + threadIdx.x;
  if (e < NE) {
    int s = srcI[e], d = dstI[e];
    int pos = atomicAdd(&cursor[d], 1);
    float v = dinv[s] * w[e] * dinv[d];
    int2 cv; cv.x = s; cv.y = __float_as_int(v);
    csr[rowptr[d] + pos] = cv;
  }
}

// GCN layer 1 fused: agg = Ahat x (8-dim gather), A1 = relu(agg@W1 + b1), BN stats.
// Wave per dst row: lane = e8*8 + c8 during gather; lane = out-channel for GEMM.
__global__ __launch_bounds__(256) void k_gcn1(const float* __restrict__ x,
                                              const float* __restrict__ dinv,
                                              const int* __restrict__ rowptr,
                                              const int2* __restrict__ csr,
                                              const float* __restrict__ W1,
                                              const float* __restrict__ b1,
                                              ushort* __restrict__ A1,
                                              float* gsum, float* gsq) {
  __shared__ float w1s[CIN * HD];
  __shared__ float b1s[HD];
  for (int i = threadIdx.x; i < CIN * HD; i += 256) w1s[i] = W1[i];
  if (threadIdx.x < HD) b1s[threadIdx.x] = b1[threadIdx.x];
  __syncthreads();
  int wid = (blockIdx.x * 256 + threadIdx.x) >> 6;
  int lane = threadIdx.x & 63;
  int nw = (gridDim.x * 256) >> 6;
  int e8 = lane >> 3, c8 = lane & 7;
  float s = 0.f, q = 0.f;
  for (int d = wid; d < N_TOT; d += nw) {
    int beg = rowptr[d], end = rowptr[d + 1];
    float part = 0.f;
    for (int i = beg + e8; i < end; i += 8) {
      int2 cv = csr[i];
      part += __int_as_float(cv.y) * x[(size_t)cv.x * CIN + c8];
    }
    part += __shfl_xor(part, 8);
    part += __shfl_xor(part, 16);
    part += __shfl_xor(part, 32);
    float di = dinv[d];
    float di2 = di * di;
    float xd = x[(size_t)d * CIN + c8];
    float acc = b1s[lane];
    #pragma unroll
    for (int c = 0; c < CIN; ++c) {
      float aggc = __shfl(part, c) + di2 * __shfl(xd, c);
      acc += aggc * w1s[c * HD + lane];
    }
    float r = fmaxf(acc, 0.f);
    A1[(size_t)d * HD + lane] = f2bf(r);
    s += r; q += r * r;
  }
  atomicAdd(&gsum[lane], s);
  atomicAdd(&gsq[lane], q);
}

__global__ __launch_bounds__(64) void k_bnfin(const float* __restrict__ gsum,
                                              const float* __restrict__ gsq,
                                              const float* __restrict__ gamma,
                                              const float* __restrict__ beta,
                                              float* __restrict__ scale,
                                              float* __restrict__ shift) {
  int j = threadIdx.x;
  if (j < HD) {
    float m = gsum[j] / (float)N_TOT;
    float v = gsq[j] / (float)N_TOT - m * m;
    float sc = gamma[j] * rsqrtf(v + 1e-5f);
    scale[j] = sc;
    shift[j] = beta[j] - m * sc;
  }
}

// Hb = bf16( BN1(A1) @ W2 )  ([N,64]@[64,64]); wave per row; W2 is [k][j] layout
__global__ __launch_bounds__(256) void k_gemm_h(const ushort* __restrict__ A1,
                                                const float* __restrict__ scale,
                                                const float* __restrict__ shift,
                                                const float* __restrict__ W2,
                                                ushort* __restrict__ Hb) {
  __shared__ float w[HD * HD];
  for (int i = threadIdx.x; i < HD * HD; i += 256) w[i] = W2[i];
  __syncthreads();
  int wid = (blockIdx.x * 256 + threadIdx.x) >> 6;
  int lane = threadIdx.x & 63;
  int nw = (gridDim.x * 256) >> 6;
  float sc = scale[lane], sh = shift[lane];
  for (int n = wid; n < N_TOT; n += nw) {
    float xj = sc * bf2f(A1[(size_t)n * HD + lane]) + sh;
    float acc = 0.f;
    #pragma unroll 8
    for (int k = 0; k < HD; ++k) acc += __shfl(xj, k, 64) * w[k * HD + lane];
    Hb[(size_t)n * HD + lane] = f2bf(acc);
  }
}

// GCN layer 2 aggregation: A2 = relu( Ahat Hb + b2 ), bf16 gathers, BN stats.
__global__ __launch_bounds__(256) void k_spmm2(const ushort* __restrict__ Hb,
                                               const float* __restrict__ dinv,
                                               const int* __restrict__ rowptr,
                                               const int2* __restrict__ csr,
                                               const float* __restrict__ bias,
                                               ushort* __restrict__ A2,
                                               float* gsum, float* gsq) {
  int wid = (blockIdx.x * 256 + threadIdx.x) >> 6;
  int lane = threadIdx.x & 63;
  int nw = (gridDim.x * 256) >> 6;
  float b = bias[lane];
  float s = 0.f, q = 0.f;
  for (int d = wid; d < N_TOT; d += nw) {
    float di = dinv[d];
    float acc = di * di * bf2f(Hb[(size_t)d * HD + lane]);
    int beg = rowptr[d], end = rowptr[d + 1];
    #pragma unroll 4
    for (int i = beg; i < end; ++i) {
      int2 cv = csr[i];
      acc += __int_as_float(cv.y) * bf2f(Hb[(size_t)cv.x * HD + lane]);
    }
    float r = fmaxf(acc + b, 0.f);
    A2[(size_t)d * HD + lane] = f2bf(r);
    s += r; q += r * r;
  }
  atomicAdd(&gsum[lane], s);
  atomicAdd(&gsq[lane], q);
}

// ---------------------------------------------------------------------------
// Barrier-free fused 2-layer LSTM, q-split to bound register pressure.
// One wave owns 16 nodes for all 7 steps. Per q in 0..3: gates i,f,g,o live at
// nt = {q,4+q,8+q,12+q} -> acc[4] only. h1/h2 kept in per-wave LDS, double-
// buffered by step parity (q-passes would otherwise overwrite h being read).
// A-fragments for Xc are direct 16B loads from raw A1/A2 bf16 (BN folded into
// Wp1/biasL1). No __syncthreads anywhere.
// ---------------------------------------------------------------------------
__global__ __launch_bounds__(256, 4) void k_lstm4(const ushort* __restrict__ A1,
                                                  const ushort* __restrict__ A2,
                                                  const ushort* __restrict__ Wp1,
                                                  const ushort* __restrict__ Wphh1,
                                                  const ushort* __restrict__ Wpih2,
                                                  const ushort* __restrict__ Wphh2,
                                                  const float* __restrict__ biasL1,
                                                  const float* __restrict__ bsum2,
                                                  float* __restrict__ out) {
  __shared__ ushort hbuf[4][2][2][1024];   // [wave][h1|h2][parity][16x64 swizzled]
  int t = threadIdx.x;
  int wid = t >> 6, lane = t & 63;
  int tile = blockIdx.x * 4 + wid;
  if (tile >= NTILES) return;
  int g = lane >> 4, c = lane & 15;

  float c1[16], c2[16];
  #pragma unroll
  for (int i = 0; i < 16; ++i) { c1[i] = 0.f; c2[i] = 0.f; }

  // A-fragment read offsets into h buffers (ushort units, XOR-swizzled)
  int hr[2];
  #pragma unroll
  for (int kc = 0; kc < 2; ++kc)
    hr[kc] = (c * 64 + kc * 32 + g * 8) ^ ((c & 7) << 3);

  for (int step = 0; step < TWIN; ++step) {
    int pw = step & 1, pr = pw ^ 1;
    ushort* h1w = &hbuf[wid][0][pw][0];
    ushort* h1r = &hbuf[wid][0][pr][0];
    ushort* h2w = &hbuf[wid][1][pw][0];
    ushort* h2r = &hbuf[wid][1][pr][0];
    size_t nodeoff = (size_t)(step * NODES + tile * 16 + c) * HD + g * 8;
    const ushort* a1p = A1 + nodeoff;
    const ushort* a2p = A2 + nodeoff;

    // ===== layer 1 =====
    #pragma unroll 1
    for (int q = 0; q < 4; ++q) {
      f32x4 acc[4];
      #pragma unroll
      for (int gi = 0; gi < 4; ++gi) {
        float bv = biasL1[gi * 64 + q * 16 + c];
        acc[gi] = (f32x4){bv, bv, bv, bv};
      }
      #pragma unroll
      for (int kc = 0; kc < 4; ++kc) {
        const ushort* ap = (kc < 2) ? (a1p + kc * 32) : (a2p + (kc - 2) * 32);
        short8 a = *reinterpret_cast<const short8*>(ap);
        #pragma unroll
        for (int gi = 0; gi < 4; ++gi) {
          short8 b = *reinterpret_cast<const short8*>(&Wp1[((kc * 16 + gi * 4 + q) * 64 + lane) * 8]);
          acc[gi] = __builtin_amdgcn_mfma_f32_16x16x32_bf16(a, b, acc[gi], 0, 0, 0);
        }
      }
      if (step > 0) {
        #pragma unroll
        for (int kc = 0; kc < 2; ++kc) {
          short8 a = *reinterpret_cast<const short8*>(&h1r[hr[kc]]);
          #pragma unroll
          for (int gi = 0; gi < 4; ++gi) {
            short8 b = *reinterpret_cast<const short8*>(&Wphh1[((kc * 16 + gi * 4 + q) * 64 + lane) * 8]);
            acc[gi] = __builtin_amdgcn_mfma_f32_16x16x32_bf16(a, b, acc[gi], 0, 0, 0);
          }
        }
      }
      #pragma unroll
      for (int jr = 0; jr < 4; ++jr) {
        float gi_ = acc[0][jr], gf = acc[1][jr], gg = acc[2][jr], go = acc[3][jr];
        float cc = sigf(gf) * c1[q * 4 + jr] + sigf(gi_) * tanhf_(gg);
        c1[q * 4 + jr] = cc;
        float h = sigf(go) * tanhf_(cc);
        int r = g * 4 + jr, j = q * 16 + c;
        h1w[(r * 64 + j) ^ ((r & 7) << 3)] = f2bf(h);
        if (step == TWIN - 1) out[(size_t)(tile * 16 + r) * OUTC + j] = h;
      }
    }

    // ===== layer 2 =====
    #pragma unroll 1
    for (int q = 0; q < 4; ++q) {
      f32x4 acc[4];
      #pragma unroll
      for (int gi = 0; gi < 4; ++gi) {
        float bv = bsum2[gi * 64 + q * 16 + c];
        acc[gi] = (f32x4){bv, bv, bv, bv};
      }
      #pragma unroll
      for (int kc = 0; kc < 2; ++kc) {
        short8 a = *reinterpret_cast<const short8*>(&h1w[hr[kc]]);
        #pragma unroll
        for (int gi = 0; gi < 4; ++gi) {
          short8 b = *reinterpret_cast<const short8*>(&Wpih2[((kc * 16 + gi * 4 + q) * 64 + lane) * 8]);
          acc[gi] = __builtin_amdgcn_mfma_f32_16x16x32_bf16(a, b, acc[gi], 0, 0, 0);
        }
      }
      if (step > 0) {
        #pragma unroll
        for (int kc = 0; kc < 2; ++kc) {
          short8 a = *reinterpret_cast<const short8*>(&h2r[hr[kc]]);
          #pragma unroll
          for (int gi = 0; gi < 4; ++gi) {
            short8 b = *reinterpret_cast<const short8*>(&Wphh2[((kc * 16 + gi * 4 + q) * 64 + lane) * 8]);
            acc[gi] = __builtin_amdgcn_mfma_f32_16x16x32_bf16(a, b, acc[gi], 0, 0, 0);
          }
        }
      }
      #pragma unroll
      for (int jr = 0; jr < 4; ++jr) {
        float gi_ = acc[0][jr], gf = acc[1][jr], gg = acc[2][jr], go = acc[3][jr];
        float cc = sigf(gf) * c2[q * 4 + jr] + sigf(gi_) * tanhf_(gg);
        c2[q * 4 + jr] = cc;
        float h = sigf(go) * tanhf_(cc);
        int r = g * 4 + jr, j = q * 16 + c;
        h2w[(r * 64 + j) ^ ((r & 7) << 3)] = f2bf(h);
        if (step == TWIN - 1) out[(size_t)(tile * 16 + r) * OUTC + HD + j] = h;
      }
    }
  }
}

// skip connection S -> out cols 128..141
__global__ __launch_bounds__(256) void k_out_s(const float* __restrict__ x,
                                               float* __restrict__ out) {
  int idx = blockIdx.x * 256 + threadIdx.x;
  if (idx < NODES * 14) {
    int n = idx / 14, c = idx - n * 14;
    float v = (c < CIN) ? x[n * CIN + c]
                        : x[((c - (CIN - 1)) * NODES + n) * CIN + (CIN - 1)];
    out[(size_t)n * OUTC + 128 + c] = v;
  }
}

extern "C" void kernel_launch(void* const* d_in, const int* in_sizes, int n_in,
                              void* d_out, int out_size, void* d_ws, size_t ws_size,
                              hipStream_t stream) {
  const float* x      = (const float*)d_in[0];
  const int*   ei     = (const int*)d_in[1];
  const float* ew     = (const float*)d_in[2];
  const float* W1     = (const float*)d_in[3];
  const float* b1     = (const float*)d_in[4];
  const float* W2     = (const float*)d_in[5];
  const float* b2     = (const float*)d_in[6];
  const float* gamma1 = (const float*)d_in[7];
  const float* beta1  = (const float*)d_in[8];
  const float* gamma2 = (const float*)d_in[9];
  const float* beta2  = (const float*)d_in[10];
  const float* Wih1   = (const float*)d_in[11];
  const float* Whh1   = (const float*)d_in[12];
  const float* bih1   = (const float*)d_in[13];
  const float* bhh1   = (const float*)d_in[14];
  const float* Wih2   = (const float*)d_in[15];
  const float* Whh2   = (const float*)d_in[16];
  const float* bih2   = (const float*)d_in[17];
  const float* bhh2   = (const float*)d_in[18];
  const int* srcI = ei;
  const int* dstI = ei + NE;
  float* out = (float*)d_out;

  char* base = (char*)d_ws;
  size_t off = 0;
  auto alloc = [&](size_t bytes) -> void* {
    void* p = base + off;
    off = (off + bytes + 255) & ~(size_t)255;
    return p;
  };
  // small
  float* deg    = (float*)alloc(N_TOT * 4);
  float* dinv   = (float*)alloc(N_TOT * 4);
  int*   rowptr = (int*)alloc((N_TOT + 1) * 4);
  int*   bsum   = (int*)alloc(NB_SCAN * 4);
  ushort* Wp1   = (ushort*)alloc(32768 * 2);   // [4kc][16nt][64][8] (BN-scaled)
  ushort* Wphh1 = (ushort*)alloc(16384 * 2);
  ushort* Wpih2 = (ushort*)alloc(16384 * 2);
  ushort* Wphh2 = (ushort*)alloc(16384 * 2);
  float* biasL1 = (float*)alloc(256 * 4);
  float* bsum2  = (float*)alloc(256 * 4);
  float* scale1 = (float*)alloc(HD * 4);
  float* shift1 = (float*)alloc(HD * 4);
  float* scale2 = (float*)alloc(HD * 4);
  float* shift2 = (float*)alloc(HD * 4);
  // zeroed-every-call region (contiguous)
  char* zstart = base + off;
  int*   cnt    = (int*)alloc(N_TOT * 4);
  int*   cursor = (int*)alloc(N_TOT * 4);
  float* sum1   = (float*)alloc(HD * 4);
  float* sq1    = (float*)alloc(HD * 4);
  float* sum2   = (float*)alloc(HD * 4);
  float* sq2    = (float*)alloc(HD * 4);
  size_t zbytes = (size_t)((base + off) - zstart);
  // big buffers (~72 MB)
  int2*   csr = (int2*)alloc((size_t)NE * 8);
  ushort* Hb  = (ushort*)alloc((size_t)N_TOT * HD * 2);
  ushort* A1  = (ushort*)alloc((size_t)N_TOT * HD * 2);
  ushort* A2  = (ushort*)alloc((size_t)N_TOT * HD * 2);

  hipMemsetAsync(zstart, 0, zbytes, stream);
  k_init_deg<<<(N_TOT + 255) / 256, 256, 0, stream>>>(deg);
  k_pack<<<(16384 + 255) / 256, 256, 0, stream>>>(Whh1, Wphh1, 64);
  k_pack<<<(16384 + 255) / 256, 256, 0, stream>>>(Wih2, Wpih2, 64);
  k_pack<<<(16384 + 255) / 256, 256, 0, stream>>>(Whh2, Wphh2, 64);
  k_bsum2<<<1, 256, 0, stream>>>(bih2, bhh2, bsum2);
  k_deg_cnt<<<(NE + 255) / 256, 256, 0, stream>>>(srcI, dstI, ew, deg, cnt);
  k_dinv<<<(N_TOT + 255) / 256, 256, 0, stream>>>(deg, dinv);
  k_scan_a<<<NB_SCAN, 256, 0, stream>>>(cnt, bsum, N_TOT);
  k_scan_b<<<1, 64, 0, stream>>>(bsum, NB_SCAN);
  k_scan_c<<<NB_SCAN, 256, 0, stream>>>(cnt, bsum, rowptr, N_TOT, NE);
  k_fill<<<(NE + 255) / 256, 256, 0, stream>>>(srcI, dstI, ew, dinv, rowptr, cursor, csr);
  k_gcn1<<<1024, 256, 0, stream>>>(x, dinv, rowptr, csr, W1, b1, A1, sum1, sq1);
  k_bnfin<<<1, 64, 0, stream>>>(sum1, sq1, gamma1, beta1, scale1, shift1);
  k_gemm_h<<<512, 256, 0, stream>>>(A1, scale1, shift1, W2, Hb);
  k_spmm2<<<1024, 256, 0, stream>>>(Hb, dinv, rowptr, csr, b2, A2, sum2, sq2);
  k_bnfin<<<1, 64, 0, stream>>>(sum2, sq2, gamma2, beta2, scale2, shift2);
  k_pack_s<<<(32768 + 255) / 256, 256, 0, stream>>>(Wih1, scale1, scale2, Wp1);
  k_bias1<<<1, 256, 0, stream>>>(Wih1, bih1, bhh1, shift1, shift2, biasL1);
  k_lstm4<<<(NTILES + 3) / 4, 256, 0, stream>>>(A1, A2, Wp1, Wphh1, Wpih2, Wphh2,
                                                biasL1, bsum2, out);
  k_out_s<<<(NODES * 14 + 255) / 256, 256, 0, stream>>>(x, out);
}